// Round 1
// baseline (183.404 us; speedup 1.0000x reference)
//
#include <hip/hip_runtime.h>
#include <hip/hip_bf16.h>
#include <stdint.h>

typedef __bf16 bf16;
typedef __bf16 bf16x4 __attribute__((ext_vector_type(4)));
typedef __bf16 bf16x8 __attribute__((ext_vector_type(8)));
typedef float  f32x4  __attribute__((ext_vector_type(4)));

#define L_TOT 1024
#define B_TOT 64
#define C_TOT 1024            // ENC2
#define D_TOT 512             // DEC
#define E_TOT 512
#define M_TOT (L_TOT * B_TOT) // 65536
#define K_TOT C_TOT
#define W_LD  (C_TOT + D_TOT) // 1536

#define BM 128
#define BN 512
#define BK 64
#define NTHREADS 512
#define NKT (K_TOT / BK)      // 16

// --- async global->LDS, 16B per lane (CK-style addrspace cast pattern) ---
__device__ __forceinline__ void gload_lds16(const void* g, void* l) {
  __builtin_amdgcn_global_load_lds(
      (const __attribute__((address_space(1))) unsigned int*)(uintptr_t)g,
      (__attribute__((address_space(3))) unsigned int*)(uintptr_t)l,
      16, 0, 0);
}

__device__ __forceinline__ bf16x4 cvt4(float4 v) {
  bf16x4 o;
  o[0] = (bf16)v.x; o[1] = (bf16)v.y; o[2] = (bf16)v.z; o[3] = (bf16)v.w;
  return o;
}

// ---- prep: Wa_e (fp32, row stride 1536) -> bf16 [512][1024] in ws ----
__global__ void convert_we_kernel(const float* __restrict__ Wattn,
                                  bf16* __restrict__ Wb) {
  const int e = blockIdx.x;   // 512
  const int t = threadIdx.x;  // 256, float4 each = 1024 floats/row
  const float4 v = ((const float4*)(Wattn + (size_t)e * W_LD))[t];
  ((bf16x4*)(Wb + (size_t)e * C_TOT))[t] = cvt4(v);
}

// ---- prep: sb[b][e] = sum_d s[b,d] * Wa_s[e,d]  (fp32, tiny) ----
__global__ void sb_kernel(const float* __restrict__ s,
                          const float* __restrict__ Wattn,
                          float* __restrict__ sb) {
  const int e = blockIdx.x;   // 512
  const int b = threadIdx.x;  // 64 (one wave)
  const float4* sr = (const float4*)(s + (size_t)b * D_TOT);
  const float4* wr = (const float4*)(Wattn + (size_t)e * W_LD + C_TOT);
  float acc = 0.f;
#pragma unroll 4
  for (int i = 0; i < D_TOT / 4; ++i) {
    float4 a = sr[i], w = wr[i];
    acc += a.x * w.x; acc += a.y * w.y; acc += a.z * w.z; acc += a.w * w.w;
  }
  sb[(size_t)b * E_TOT + e] = acc;
}

// ---- main: pre = enc·Wa_e^T (+sb), tanh, ·Wv, reduce over e -> logits[m] ----
// block: 128 m-rows x full 512 e.  8 waves = 2(m) x 4(n); wave tile 64x128.
// LDS: A [128][64]bf16 (16KB, XOR-swizzled) + B [512][64]bf16 (64KB, swizzled
// via source-XOR on global_load_lds).  Swizzle: byte ^= ((row&7)<<4) in-row.
__global__ __launch_bounds__(NTHREADS, 2)
void gemm_tanh_dot_kernel(const float* __restrict__ A,
                          const bf16*  __restrict__ Wb,
                          const float* __restrict__ sb,
                          const float* __restrict__ Wv,
                          float* __restrict__ logits) {
  __shared__ __align__(16) char smem[(BM * BK + BN * BK) * 2]; // 80 KB
  char* As = smem;                   // [128][64] bf16
  char* Bs = smem + BM * BK * 2;     // [512][64] bf16

  const int tid  = threadIdx.x;
  const int lane = tid & 63;
  const int wid  = tid >> 6;
  const int wm   = wid >> 2;         // 0..1
  const int wn   = wid & 3;          // 0..3
  const int fr   = lane & 15;
  const int fg   = lane >> 4;
  const int m0   = blockIdx.x * BM;

  // A staging: thread covers 16B seg (a_row, a_col), 4 j-steps of +32 rows.
  const int a_row = tid >> 4;        // 0..31
  const int a_col = tid & 15;        // 16B seg within 256B row-chunk
  const float* aG = A + (size_t)(m0 + a_row) * K_TOT + a_col * 4;
  const int a_sw  = ((((a_col >> 1) ^ (a_row & 7)) << 4) | ((a_col & 1) << 3));

  // B staging: wave wid stages rows [wid*64, +64); 8 issues x 8 rows.
  const int b_row = (wid << 6) + (lane >> 3);
  const int b_xor = ((lane & 7) ^ (lane >> 3)) << 3;  // element offset (inv-swz src)
  const bf16* bG  = Wb + (size_t)b_row * K_TOT + b_xor;
  char* b_dst     = Bs + (wid << 13) + (lane << 4);   // linear dest (base+lane*16)

  f32x4 acc[4][8];
#pragma unroll
  for (int i = 0; i < 4; ++i)
#pragma unroll
    for (int j = 0; j < 8; ++j)
      acc[i][j] = (f32x4){0.f, 0.f, 0.f, 0.f};

  const char* Arow = As + ((wm << 6) + fr) * 128;
  const char* Brow = Bs + ((wn << 7) + fr) * 128;

  // prologue A prefetch (kt = 0)
  float4 av0 = *(const float4*)(aG);
  float4 av1 = *(const float4*)(aG + 32 * K_TOT);
  float4 av2 = *(const float4*)(aG + 64 * K_TOT);
  float4 av3 = *(const float4*)(aG + 96 * K_TOT);

#pragma unroll 1
  for (int kt = 0; kt < NKT; ++kt) {
    const int k0 = kt * BK;
    __syncthreads();                        // prev compute done reading LDS
    // issue B global->LDS for this k-tile
#pragma unroll
    for (int i = 0; i < 8; ++i)
      gload_lds16(bG + k0 + i * 8 * K_TOT, b_dst + i * 1024);
    // convert + swizzled ds_write of prefetched A
    *(bf16x4*)(As + (a_row +  0) * 128 + a_sw) = cvt4(av0);
    *(bf16x4*)(As + (a_row + 32) * 128 + a_sw) = cvt4(av1);
    *(bf16x4*)(As + (a_row + 64) * 128 + a_sw) = cvt4(av2);
    *(bf16x4*)(As + (a_row + 96) * 128 + a_sw) = cvt4(av3);
    __syncthreads();                        // drains B-lds (+any vmem)
    // prefetch next A tile; latency hides under the MFMA phase below
    const int k1 = (kt + 1 < NKT) ? (k0 + BK) : 0;
    av0 = *(const float4*)(aG + k1);
    av1 = *(const float4*)(aG + k1 + 32 * K_TOT);
    av2 = *(const float4*)(aG + k1 + 64 * K_TOT);
    av3 = *(const float4*)(aG + k1 + 96 * K_TOT);
    // compute: 2 k-steps of 32, 4x8 MFMAs each
#pragma unroll
    for (int kk = 0; kk < 2; ++kk) {
      const int xo = (((kk << 2) + fg) ^ (fr & 7)) << 4;
      bf16x8 af[4];
      bf16x8 bfrag[8];
#pragma unroll
      for (int am = 0; am < 4; ++am)
        af[am] = *(const bf16x8*)(Arow + (am << 4) * 128 + xo);
#pragma unroll
      for (int bn = 0; bn < 8; ++bn)
        bfrag[bn] = *(const bf16x8*)(Brow + (bn << 4) * 128 + xo);
#pragma unroll
      for (int am = 0; am < 4; ++am)
#pragma unroll
        for (int bn = 0; bn < 8; ++bn)
          acc[am][bn] = __builtin_amdgcn_mfma_f32_16x16x32_bf16(
              af[am], bfrag[bn], acc[am][bn], 0, 0, 0);
    }
  }

  // ---- fused epilogue: +sb, tanh, *Wv, reduce over e ----
  float wv[8];
#pragma unroll
  for (int bn = 0; bn < 8; ++bn)
    wv[bn] = Wv[(wn << 7) + (bn << 4) + fr];

  float sums[4][4];
#pragma unroll
  for (int am = 0; am < 4; ++am) {
#pragma unroll
    for (int j = 0; j < 4; ++j) {
      const int mloc = (wm << 6) + (am << 4) + (fg << 2) + j;
      const int b = (m0 + mloc) & 63;       // m = l*64 + b
      const float* sbr = sb + (size_t)b * E_TOT + (wn << 7) + fr;
      float c = 0.f;
#pragma unroll
      for (int bn = 0; bn < 8; ++bn) {
        float v = acc[am][bn][j] + sbr[bn << 4];
        c += tanhf(v) * wv[bn];
      }
      // reduce across the 16-lane group (covers 16 e's; bn loop covered 8)
      c += __shfl_xor(c, 1, 64);
      c += __shfl_xor(c, 2, 64);
      c += __shfl_xor(c, 4, 64);
      c += __shfl_xor(c, 8, 64);
      sums[am][j] = c;
    }
  }

  __syncthreads();                          // all waves done with As/Bs
  float* red = (float*)smem;                // reuse LDS: [4 wn][128 m]
  if (fr == 0) {
#pragma unroll
    for (int am = 0; am < 4; ++am)
#pragma unroll
      for (int j = 0; j < 4; ++j)
        red[(wn << 7) + (wm << 6) + (am << 4) + (fg << 2) + j] = sums[am][j];
  }
  __syncthreads();
  if (tid < BM) {
    float v = red[tid] + red[128 + tid] + red[256 + tid] + red[384 + tid];
    logits[m0 + tid] = v;
  }
}

// ---- softmax over l per b; logits[m] with m = l*64+b; out[b][l] ----
__global__ __launch_bounds__(256)
void softmax_kernel(const float* __restrict__ logits, float* __restrict__ out) {
  const int b = blockIdx.x;   // 64
  const int t = threadIdx.x;  // 256, 4 l's each
  const int lane = t & 63, w = t >> 6;
  __shared__ float sm[8];
  float x[4];
  float mx = -3.4e38f;
#pragma unroll
  for (int i = 0; i < 4; ++i) {
    const int l = t + (i << 8);
    x[i] = logits[(size_t)l * 64 + b];
    mx = fmaxf(mx, x[i]);
  }
#pragma unroll
  for (int off = 1; off < 64; off <<= 1)
    mx = fmaxf(mx, __shfl_xor(mx, off, 64));
  if (lane == 0) sm[w] = mx;
  __syncthreads();
  mx = fmaxf(fmaxf(sm[0], sm[1]), fmaxf(sm[2], sm[3]));
  float ex[4], ssum = 0.f;
#pragma unroll
  for (int i = 0; i < 4; ++i) { ex[i] = expf(x[i] - mx); ssum += ex[i]; }
#pragma unroll
  for (int off = 1; off < 64; off <<= 1)
    ssum += __shfl_xor(ssum, off, 64);
  if (lane == 0) sm[4 + w] = ssum;
  __syncthreads();
  const float inv = 1.0f / (sm[4] + sm[5] + sm[6] + sm[7]);
#pragma unroll
  for (int i = 0; i < 4; ++i)
    out[(size_t)b * 1024 + t + (i << 8)] = ex[i] * inv;
}

extern "C" void kernel_launch(void* const* d_in, const int* in_sizes, int n_in,
                              void* d_out, int out_size, void* d_ws, size_t ws_size,
                              hipStream_t stream) {
  const float* enc = (const float*)d_in[0];  // (1024, 64, 1024) fp32
  const float* s   = (const float*)d_in[1];  // (1, 64, 512)     fp32
  const float* Wat = (const float*)d_in[2];  // (512, 1536)      fp32
  const float* Wv  = (const float*)d_in[3];  // (1, 512)         fp32
  float* out = (float*)d_out;                // (64, 1024)       fp32

  char* ws = (char*)d_ws;                    // need ~1.4 MB
  bf16*  Wb     = (bf16*)ws;                               // 1 MB
  float* sb     = (float*)(ws + (1u << 20));               // 128 KB
  float* logits = (float*)(ws + (1u << 20) + (128u << 10));// 256 KB

  convert_we_kernel<<<E_TOT, 256, 0, stream>>>(Wat, Wb);
  sb_kernel<<<E_TOT, 64, 0, stream>>>(s, Wat, sb);
  gemm_tanh_dot_kernel<<<M_TOT / BM, NTHREADS, 0, stream>>>(enc, Wb, sb, Wv, logits);
  softmax_kernel<<<B_TOT, 256, 0, stream>>>(logits, out);
}

// Round 2
// 178.600 us; speedup vs baseline: 1.0269x; 1.0269x over previous
//
#include <hip/hip_runtime.h>
#include <hip/hip_bf16.h>
#include <stdint.h>

typedef __bf16 bf16;
typedef __bf16 bf16x4 __attribute__((ext_vector_type(4)));
typedef __bf16 bf16x8 __attribute__((ext_vector_type(8)));
typedef float  f32x4  __attribute__((ext_vector_type(4)));

#define L_TOT 1024
#define B_TOT 64
#define C_TOT 1024            // ENC2 (= K)
#define D_TOT 512             // DEC
#define E_TOT 512
#define M_TOT (L_TOT * B_TOT) // 65536
#define W_LD  (C_TOT + D_TOT) // 1536

#define BM 64
#define BN 512
#define BK 32
#define NT 512
#define NKT (C_TOT / BK)      // 32

// --- async global->LDS, 16B per lane ---
__device__ __forceinline__ void gload_lds16(const void* g, void* l) {
  __builtin_amdgcn_global_load_lds(
      (const __attribute__((address_space(1))) unsigned int*)(uintptr_t)g,
      (__attribute__((address_space(3))) unsigned int*)(uintptr_t)l,
      16, 0, 0);
}

__device__ __forceinline__ bf16x4 cvt4(float4 v) {
  bf16x4 o;
  o[0] = (bf16)v.x; o[1] = (bf16)v.y; o[2] = (bf16)v.z; o[3] = (bf16)v.w;
  return o;
}

// ---- prep: Wa_e (fp32, row stride 1536) -> bf16 [512][1024] in ws ----
__global__ void convert_we_kernel(const float* __restrict__ Wattn,
                                  bf16* __restrict__ Wb) {
  const int e = blockIdx.x;   // 512
  const int t = threadIdx.x;  // 256
  const float4 v = ((const float4*)(Wattn + (size_t)e * W_LD))[t];
  ((bf16x4*)(Wb + (size_t)e * C_TOT))[t] = cvt4(v);
}

// ---- prep: sb[b][e] = sum_d s[b,d] * Wa_s[e,d] ----
__global__ void sb_kernel(const float* __restrict__ s,
                          const float* __restrict__ Wattn,
                          float* __restrict__ sb) {
  const int e = blockIdx.x;   // 512
  const int b = threadIdx.x;  // 64
  const float4* sr = (const float4*)(s + (size_t)b * D_TOT);
  const float4* wr = (const float4*)(Wattn + (size_t)e * W_LD + C_TOT);
  float acc = 0.f;
#pragma unroll 4
  for (int i = 0; i < D_TOT / 4; ++i) {
    float4 a = sr[i], w = wr[i];
    acc += a.x * w.x; acc += a.y * w.y; acc += a.z * w.z; acc += a.w * w.w;
  }
  sb[(size_t)b * E_TOT + e] = acc;
}

// ---- main GEMM + fused tanh/dot epilogue ----
// Block: 64 m-rows (= one l, all 64 b's) x full 512 e.  8 waves, wave wn owns
// e-range [wn*64, +64).  Double-buffered LDS: A 2x4KB, B 2x32KB = 72KB
// (2 blocks/CU).  Paired-row swizzled layout: logical row r lives at
// r' = r>>1 (128B rows); 16B seg index s = (r&1)*4 + k8, stored at s^(r'&7).
__global__ __launch_bounds__(NT, 4)
void gemm_tanh_dot_kernel(const float* __restrict__ A,
                          const bf16*  __restrict__ Wb,
                          const float* __restrict__ sb,
                          const float* __restrict__ Wv,
                          float* __restrict__ logits) {
  __shared__ __align__(16) char smem[2 * 4096 + 2 * 32768];  // 72 KB
  char* const As0 = smem;
  char* const As1 = smem + 4096;
  char* const Bs0 = smem + 8192;
  char* const Bs1 = smem + 8192 + 32768;

  const int tid  = threadIdx.x;
  const int lane = tid & 63;
  const int wn   = tid >> 6;         // 0..7 : e-slice
  const int fr   = lane & 15;
  const int fg   = lane >> 4;
  const int m0   = blockIdx.x * BM;

  // A staging: thread -> (row=tid>>3, 4 floats at k4=(tid&7)*4)
  const int a_row = tid >> 3;
  const int a_k4  = (tid & 7) << 2;
  const float* gA = A + (size_t)(m0 + a_row) * C_TOT + a_k4;
  const int a_s   = ((a_row & 1) << 2) | (a_k4 >> 3);
  const int aw_off = ((a_row >> 1) << 7)
                   + ((a_s ^ ((a_row >> 1) & 7)) << 4)
                   + ((a_k4 & 4) << 1);

  // B staging: linear LDS dest (tid*16 + i*8192), inverse-swizzled global src
  const int b_s = (tid & 7) ^ ((tid >> 3) & 7);
  const int b_e = ((tid >> 3) << 1) + (b_s >> 2);
  const bf16* bsrc = Wb + (size_t)b_e * C_TOT + ((b_s & 3) << 3);
  const int b_dst = tid << 4;

  // fragment read offset (shared by A and B): row r = 16*idx + fr, seg fg
  const int xo = ((((fr & 1) << 2) | fg) ^ ((fr >> 1) & 7)) << 4;
  const int ro = ((fr >> 1) << 7) + xo;

  f32x4 acc[4][4];
#pragma unroll
  for (int i = 0; i < 4; ++i)
#pragma unroll
    for (int j = 0; j < 4; ++j)
      acc[i][j] = (f32x4){0.f, 0.f, 0.f, 0.f};

  // prologue: stage tile 0, prefetch A regs for tile 1
  float4 avA = *(const float4*)(gA);
#pragma unroll
  for (int i = 0; i < 4; ++i)
    gload_lds16(bsrc + i * 131072, Bs0 + b_dst + i * 8192);
  *(bf16x4*)(As0 + aw_off) = cvt4(avA);
  avA = *(const float4*)(gA + BK);
  __syncthreads();

  char* Ac = As0; char* An = As1; char* Bc = Bs0; char* Bn = Bs1;
#pragma unroll 1
  for (int kt = 0; kt < NKT; ++kt) {
    if (kt + 1 < NKT) {
      const int k1 = (kt + 1) * BK;
#pragma unroll
      for (int i = 0; i < 4; ++i)
        gload_lds16(bsrc + k1 + i * 131072, Bn + b_dst + i * 8192);
      *(bf16x4*)(An + aw_off) = cvt4(avA);
      const int k2 = (kt + 2 < NKT) ? (kt + 2) * BK : 0;
      avA = *(const float4*)(gA + k2);
    }
    bf16x8 af[4], bfr[4];
#pragma unroll
    for (int am = 0; am < 4; ++am)
      af[am] = *(const bf16x8*)(Ac + am * 1024 + ro);
#pragma unroll
    for (int bn = 0; bn < 4; ++bn)
      bfr[bn] = *(const bf16x8*)(Bc + (wn << 12) + bn * 1024 + ro);
#pragma unroll
    for (int am = 0; am < 4; ++am)
#pragma unroll
      for (int bn = 0; bn < 4; ++bn)
        acc[am][bn] = __builtin_amdgcn_mfma_f32_16x16x32_bf16(
            af[am], bfr[bn], acc[am][bn], 0, 0, 0);
    __syncthreads();
    char* t0 = Ac; Ac = An; An = t0;
    char* t1 = Bc; Bc = Bn; Bn = t1;
  }

  // ---- fused epilogue: +sb, tanh, *Wv, reduce over e ----
  float wv[4];
#pragma unroll
  for (int bn = 0; bn < 4; ++bn)
    wv[bn] = Wv[(wn << 6) + (bn << 4) + fr];

  float* red = (float*)smem;  // [8 wn][64 m]; safe: final barrier passed
#pragma unroll
  for (int am = 0; am < 4; ++am) {
#pragma unroll
    for (int j = 0; j < 4; ++j) {
      const int mloc = (am << 4) + (fg << 2) + j;   // == b (BM==B_TOT)
      const float* sbr = sb + (size_t)mloc * E_TOT + (wn << 6) + fr;
      float c = 0.f;
#pragma unroll
      for (int bn = 0; bn < 4; ++bn)
        c += tanhf(acc[am][bn][j] + sbr[bn << 4]) * wv[bn];
      c += __shfl_xor(c, 1, 64);
      c += __shfl_xor(c, 2, 64);
      c += __shfl_xor(c, 4, 64);
      c += __shfl_xor(c, 8, 64);
      if (fr == 0) red[(wn << 6) + mloc] = c;
    }
  }
  __syncthreads();
  if (tid < BM) {
    float v = 0.f;
#pragma unroll
    for (int w = 0; w < 8; ++w) v += red[(w << 6) + tid];
    logits[m0 + tid] = v;
  }
}

// ---- softmax over l per b; logits[m], m = l*64+b; out[b][l] ----
__global__ __launch_bounds__(256)
void softmax_kernel(const float* __restrict__ logits, float* __restrict__ out) {
  const int b = blockIdx.x;
  const int t = threadIdx.x;
  const int lane = t & 63, w = t >> 6;
  __shared__ float sm[8];
  float x[4];
  float mx = -3.4e38f;
#pragma unroll
  for (int i = 0; i < 4; ++i) {
    const int l = t + (i << 8);
    x[i] = logits[(size_t)l * 64 + b];
    mx = fmaxf(mx, x[i]);
  }
#pragma unroll
  for (int off = 1; off < 64; off <<= 1)
    mx = fmaxf(mx, __shfl_xor(mx, off, 64));
  if (lane == 0) sm[w] = mx;
  __syncthreads();
  mx = fmaxf(fmaxf(sm[0], sm[1]), fmaxf(sm[2], sm[3]));
  float ex[4], ssum = 0.f;
#pragma unroll
  for (int i = 0; i < 4; ++i) { ex[i] = expf(x[i] - mx); ssum += ex[i]; }
#pragma unroll
  for (int off = 1; off < 64; off <<= 1)
    ssum += __shfl_xor(ssum, off, 64);
  if (lane == 0) sm[4 + w] = ssum;
  __syncthreads();
  const float inv = 1.0f / (sm[4] + sm[5] + sm[6] + sm[7]);
#pragma unroll
  for (int i = 0; i < 4; ++i)
    out[(size_t)b * 1024 + t + (i << 8)] = ex[i] * inv;
}

extern "C" void kernel_launch(void* const* d_in, const int* in_sizes, int n_in,
                              void* d_out, int out_size, void* d_ws, size_t ws_size,
                              hipStream_t stream) {
  const float* enc = (const float*)d_in[0];  // (1024, 64, 1024) fp32
  const float* s   = (const float*)d_in[1];  // (1, 64, 512)     fp32
  const float* Wat = (const float*)d_in[2];  // (512, 1536)      fp32
  const float* Wv  = (const float*)d_in[3];  // (1, 512)         fp32
  float* out = (float*)d_out;                // (64, 1024)       fp32

  char* ws = (char*)d_ws;
  bf16*  Wb     = (bf16*)ws;                                // 1 MB
  float* sb     = (float*)(ws + (1u << 20));                // 128 KB
  float* logits = (float*)(ws + (1u << 20) + (128u << 10)); // 256 KB

  convert_we_kernel<<<E_TOT, 256, 0, stream>>>(Wat, Wb);
  sb_kernel<<<E_TOT, 64, 0, stream>>>(s, Wat, sb);
  gemm_tanh_dot_kernel<<<M_TOT / BM, NT, 0, stream>>>(enc, Wb, sb, Wv, logits);
  softmax_kernel<<<B_TOT, 256, 0, stream>>>(logits, out);
}

// Round 4
// 171.325 us; speedup vs baseline: 1.0705x; 1.0425x over previous
//
#include <hip/hip_runtime.h>
#include <hip/hip_bf16.h>
#include <stdint.h>

typedef __bf16 bf16;
typedef __bf16 bf16x4 __attribute__((ext_vector_type(4)));
typedef __bf16 bf16x8 __attribute__((ext_vector_type(8)));
typedef float  f32x4  __attribute__((ext_vector_type(4)));

#define L_TOT 1024
#define B_TOT 64
#define C_TOT 1024            // ENC2 (= K)
#define D_TOT 512             // DEC
#define E_TOT 512
#define M_TOT (L_TOT * B_TOT) // 65536
#define W_LD  (C_TOT + D_TOT) // 1536

#define BM 64
#define BN 512
#define BK 32
#define NT 512
#define NKT (C_TOT / BK)      // 32

// --- async global->LDS, 16B per lane ---
__device__ __forceinline__ void gload_lds16(const void* g, void* l) {
  __builtin_amdgcn_global_load_lds(
      (const __attribute__((address_space(1))) unsigned int*)(uintptr_t)g,
      (__attribute__((address_space(3))) unsigned int*)(uintptr_t)l,
      16, 0, 0);
}

__device__ __forceinline__ bf16x4 cvt4(f32x4 v) {
  bf16x4 o;
  o[0] = (bf16)v[0]; o[1] = (bf16)v[1]; o[2] = (bf16)v[2]; o[3] = (bf16)v[3];
  return o;
}

// ---- prep: Wa_e (fp32, row stride 1536) -> bf16 [512][1024] in ws ----
__global__ void convert_we_kernel(const float* __restrict__ Wattn,
                                  bf16* __restrict__ Wb) {
  const int e = blockIdx.x;   // 512
  const int t = threadIdx.x;  // 256
  const float4 v = ((const float4*)(Wattn + (size_t)e * W_LD))[t];
  bf16x4 o;
  o[0] = (bf16)v.x; o[1] = (bf16)v.y; o[2] = (bf16)v.z; o[3] = (bf16)v.w;
  ((bf16x4*)(Wb + (size_t)e * C_TOT))[t] = o;
}

// ---- prep: sb[b][e] = sum_d s[b,d] * Wa_s[e,d] ----
__global__ void sb_kernel(const float* __restrict__ s,
                          const float* __restrict__ Wattn,
                          float* __restrict__ sb) {
  const int e = blockIdx.x;   // 512
  const int b = threadIdx.x;  // 64
  const float4* sr = (const float4*)(s + (size_t)b * D_TOT);
  const float4* wr = (const float4*)(Wattn + (size_t)e * W_LD + C_TOT);
  float acc = 0.f;
#pragma unroll 4
  for (int i = 0; i < D_TOT / 4; ++i) {
    float4 a = sr[i], w = wr[i];
    acc += a.x * w.x; acc += a.y * w.y; acc += a.z * w.z; acc += a.w * w.w;
  }
  sb[(size_t)b * E_TOT + e] = acc;
}

// ---- main GEMM + fused tanh/dot epilogue ----
// Geometry/swizzles identical to R1 (verified).  Counted-vmcnt raw-barrier
// pipeline as R2, PLUS the post-loop drain that fixes R2's crash: the wrap
// A-prefetch issued at kp=15/t0 has no consumer, so without a vmcnt(0) drain
// its write-back lands on VGPRs the allocator has reused for epilogue
// addresses (-> memory fault).
__global__ __launch_bounds__(NT, 4)
void gemm_tanh_dot_kernel(const float* __restrict__ A,
                          const bf16*  __restrict__ Wb,
                          const float* __restrict__ sb,
                          const float* __restrict__ Wv,
                          float* __restrict__ logits) {
  __shared__ __align__(16) char smem[2 * 4096 + 2 * 32768];  // 72 KB
  char* const As0 = smem;
  char* const As1 = smem + 4096;
  char* const Bs0 = smem + 8192;
  char* const Bs1 = smem + 8192 + 32768;

  const int tid  = threadIdx.x;
  const int lane = tid & 63;
  const int wn   = tid >> 6;         // 0..7 : e-slice
  const int fr   = lane & 15;
  const int fg   = lane >> 4;
  const int m0   = blockIdx.x * BM;

  // A staging: thread -> (row=tid>>3, 4 floats at k4=(tid&7)*4)
  const int a_row = tid >> 3;
  const int a_k4  = (tid & 7) << 2;
  const float* gA = A + (size_t)(m0 + a_row) * C_TOT + a_k4;
  const int a_s   = ((a_row & 1) << 2) | (a_k4 >> 3);
  const int aw_off = ((a_row >> 1) << 7)
                   + ((a_s ^ ((a_row >> 1) & 7)) << 4)
                   + ((a_k4 & 4) << 1);

  // B staging: linear LDS dest, inverse-swizzled global src
  const int b_s = (tid & 7) ^ ((tid >> 3) & 7);
  const int b_e = ((tid >> 3) << 1) + (b_s >> 2);
  const bf16* bsrc = Wb + (size_t)b_e * C_TOT + ((b_s & 3) << 3);
  const int b_dst = tid << 4;

  // fragment read offset (shared by A and B)
  const int xo = ((((fr & 1) << 2) | fg) ^ ((fr >> 1) & 7)) << 4;
  const int ro = ((fr >> 1) << 7) + xo;

  f32x4 acc[4][4];
#pragma unroll
  for (int i = 0; i < 4; ++i)
#pragma unroll
    for (int j = 0; j < 4; ++j)
      acc[i][j] = (f32x4){0.f, 0.f, 0.f, 0.f};

  auto stageB = [&](char* Bbuf, int kc) {
#pragma unroll
    for (int i = 0; i < 4; ++i)
      gload_lds16(bsrc + kc + i * 131072, Bbuf + b_dst + i * 8192);
  };
  auto compute = [&](const char* Ac, const char* Bc) {
    bf16x8 af[4], bfr[4];
#pragma unroll
    for (int am = 0; am < 4; ++am)
      af[am] = *(const bf16x8*)(Ac + am * 1024 + ro);
#pragma unroll
    for (int bn = 0; bn < 4; ++bn)
      bfr[bn] = *(const bf16x8*)(Bc + (wn << 12) + bn * 1024 + ro);
#pragma unroll
    for (int am = 0; am < 4; ++am)
#pragma unroll
      for (int bn = 0; bn < 4; ++bn)
        acc[am][bn] = __builtin_amdgcn_mfma_f32_16x16x32_bf16(
            af[am], bfr[bn], acc[am][bn], 0, 0, 0);
  };

  f32x4 av_p, av_q, av0;

  // ---- prologue: queue = [A0, B0x4] -> wait A0 -> write -> queue [B0x4, A1]
  asm volatile("global_load_dwordx4 %0, %1, off"
               : "=v"(av0) : "v"(gA) : "memory");
  stageB(Bs0, 0);
  asm volatile("s_waitcnt vmcnt(4)" ::: "memory");
  __builtin_amdgcn_sched_barrier(0);
  *(bf16x4*)(As0 + aw_off) = cvt4(av0);
  {
    const float* ap = gA + BK;
    asm volatile("global_load_dwordx4 %0, %1, off"
                 : "=v"(av_p) : "v"(ap) : "memory");
  }

#pragma unroll 1
  for (int kp = 0; kp < 16; ++kp) {
    const int t0 = kp << 1;
    // ---------- tile t0 (even): cur = {As0,Bs0}, nxt = {As1,Bs1} ----------
    asm volatile("s_waitcnt vmcnt(1) lgkmcnt(0)" ::: "memory");
    __builtin_amdgcn_s_barrier();
    {
      stageB(Bs1, (t0 + 1) * BK);
      const float* ap = gA + ((t0 + 2) & 31) * BK;
      asm volatile("global_load_dwordx4 %0, %1, off"
                   : "=v"(av_q) : "v"(ap) : "memory");
    }
    compute(As0, Bs0);
    asm volatile("s_waitcnt vmcnt(5)" ::: "memory");
    __builtin_amdgcn_sched_barrier(0);
    *(bf16x4*)(As1 + aw_off) = cvt4(av_p);
    // ---------- tile t1 (odd): cur = {As1,Bs1}, nxt = {As0,Bs0} ----------
    asm volatile("s_waitcnt vmcnt(1) lgkmcnt(0)" ::: "memory");
    __builtin_amdgcn_s_barrier();
    if (kp < 15) {
      stageB(Bs0, (t0 + 2) * BK);
      const float* ap = gA + ((t0 + 3) & 31) * BK;
      asm volatile("global_load_dwordx4 %0, %1, off"
                   : "=v"(av_p) : "v"(ap) : "memory");
    }
    compute(As1, Bs1);
    if (kp < 15) {
      asm volatile("s_waitcnt vmcnt(5)" ::: "memory");
      __builtin_amdgcn_sched_barrier(0);
      *(bf16x4*)(As0 + aw_off) = cvt4(av_q);
    }
  }

  // ---- R3 FIX: drain the dangling wrap A-prefetch before its VGPRs can be
  // reused by the epilogue.  Keep-alive use comes AFTER the drain (volatile
  // asm preserves mutual order), so the regs stay reserved until write-back.
  asm volatile("s_waitcnt vmcnt(0)" ::: "memory");
  __builtin_amdgcn_sched_barrier(0);
  asm volatile("" :: "v"(av_q));

  // ---- fused epilogue: +sb, tanh, *Wv, reduce over e ----
  float wv[4];
#pragma unroll
  for (int bn = 0; bn < 4; ++bn)
    wv[bn] = Wv[(wn << 6) + (bn << 4) + fr];

  float* red = (float*)smem;  // [8 wn][64 m]; As0 region, no pending writes
#pragma unroll
  for (int am = 0; am < 4; ++am) {
#pragma unroll
    for (int j = 0; j < 4; ++j) {
      const int mloc = (am << 4) + (fg << 2) + j;   // == b (BM==B_TOT)
      const float* sbr = sb + (size_t)mloc * E_TOT + (wn << 6) + fr;
      float c = 0.f;
#pragma unroll
      for (int bn = 0; bn < 4; ++bn)
        c += tanhf(acc[am][bn][j] + sbr[bn << 4]) * wv[bn];
      c += __shfl_xor(c, 1, 64);
      c += __shfl_xor(c, 2, 64);
      c += __shfl_xor(c, 4, 64);
      c += __shfl_xor(c, 8, 64);
      if (fr == 0) red[(wn << 6) + mloc] = c;
    }
  }
  __syncthreads();
  if (tid < BM) {
    float v = 0.f;
#pragma unroll
    for (int w = 0; w < 8; ++w) v += red[(w << 6) + tid];
    logits[m0 + tid] = v;
  }
}

// ---- softmax over l per b; logits[m], m = l*64+b; out[b][l] ----
__global__ __launch_bounds__(256)
void softmax_kernel(const float* __restrict__ logits, float* __restrict__ out) {
  const int b = blockIdx.x;
  const int t = threadIdx.x;
  const int lane = t & 63, w = t >> 6;
  __shared__ float sm[8];
  float x[4];
  float mx = -3.4e38f;
#pragma unroll
  for (int i = 0; i < 4; ++i) {
    const int l = t + (i << 8);
    x[i] = logits[(size_t)l * 64 + b];
    mx = fmaxf(mx, x[i]);
  }
#pragma unroll
  for (int off = 1; off < 64; off <<= 1)
    mx = fmaxf(mx, __shfl_xor(mx, off, 64));
  if (lane == 0) sm[w] = mx;
  __syncthreads();
  mx = fmaxf(fmaxf(sm[0], sm[1]), fmaxf(sm[2], sm[3]));
  float ex[4], ssum = 0.f;
#pragma unroll
  for (int i = 0; i < 4; ++i) { ex[i] = expf(x[i] - mx); ssum += ex[i]; }
#pragma unroll
  for (int off = 1; off < 64; off <<= 1)
    ssum += __shfl_xor(ssum, off, 64);
  if (lane == 0) sm[4 + w] = ssum;
  __syncthreads();
  const float inv = 1.0f / (sm[4] + sm[5] + sm[6] + sm[7]);
#pragma unroll
  for (int i = 0; i < 4; ++i)
    out[(size_t)b * 1024 + t + (i << 8)] = ex[i] * inv;
}

extern "C" void kernel_launch(void* const* d_in, const int* in_sizes, int n_in,
                              void* d_out, int out_size, void* d_ws, size_t ws_size,
                              hipStream_t stream) {
  const float* enc = (const float*)d_in[0];  // (1024, 64, 1024) fp32
  const float* s   = (const float*)d_in[1];  // (1, 64, 512)     fp32
  const float* Wat = (const float*)d_in[2];  // (512, 1536)      fp32
  const float* Wv  = (const float*)d_in[3];  // (1, 512)         fp32
  float* out = (float*)d_out;                // (64, 1024)       fp32

  char* ws = (char*)d_ws;
  bf16*  Wb     = (bf16*)ws;                                // 1 MB
  float* sb     = (float*)(ws + (1u << 20));                // 128 KB
  float* logits = (float*)(ws + (1u << 20) + (128u << 10)); // 256 KB

  convert_we_kernel<<<E_TOT, 256, 0, stream>>>(Wat, Wb);
  sb_kernel<<<E_TOT, 64, 0, stream>>>(s, Wat, sb);
  gemm_tanh_dot_kernel<<<M_TOT / BM, NT, 0, stream>>>(enc, Wb, sb, Wv, logits);
  softmax_kernel<<<B_TOT, 256, 0, stream>>>(logits, out);
}

// Round 5
// 160.911 us; speedup vs baseline: 1.1398x; 1.0647x over previous
//
#include <hip/hip_runtime.h>
#include <hip/hip_bf16.h>
#include <stdint.h>

typedef __bf16 bf16;
typedef __bf16 bf16x4 __attribute__((ext_vector_type(4)));
typedef __bf16 bf16x8 __attribute__((ext_vector_type(8)));
typedef float  f32x4  __attribute__((ext_vector_type(4)));

#define L_TOT 1024
#define B_TOT 64
#define C_TOT 1024            // ENC2 (= K)
#define D_TOT 512             // DEC
#define E_TOT 512
#define M_TOT (L_TOT * B_TOT) // 65536
#define W_LD  (C_TOT + D_TOT) // 1536

#define BM 128
#define BN 512
#define BK 32
#define NT 512
#define NKT (C_TOT / BK)      // 32

// --- async global->LDS, 16B per lane ---
__device__ __forceinline__ void gload_lds16(const void* g, void* l) {
  __builtin_amdgcn_global_load_lds(
      (const __attribute__((address_space(1))) unsigned int*)(uintptr_t)g,
      (__attribute__((address_space(3))) unsigned int*)(uintptr_t)l,
      16, 0, 0);
}

// ---- prep: Wa_e (fp32, row stride 1536) -> bf16 [512][1024] in ws ----
__global__ void convert_we_kernel(const float* __restrict__ Wattn,
                                  bf16* __restrict__ Wb) {
  const int e = blockIdx.x;   // 512
  const int t = threadIdx.x;  // 256
  const float4 v = ((const float4*)(Wattn + (size_t)e * W_LD))[t];
  bf16x4 o;
  o[0] = (bf16)v.x; o[1] = (bf16)v.y; o[2] = (bf16)v.z; o[3] = (bf16)v.w;
  ((bf16x4*)(Wb + (size_t)e * C_TOT))[t] = o;
}

// ---- prep: sb[b][e] = sum_d s[b,d] * Wa_s[e,d] ----
__global__ void sb_kernel(const float* __restrict__ s,
                          const float* __restrict__ Wattn,
                          float* __restrict__ sb) {
  const int e = blockIdx.x;   // 512
  const int b = threadIdx.x;  // 64
  const float4* sr = (const float4*)(s + (size_t)b * D_TOT);
  const float4* wr = (const float4*)(Wattn + (size_t)e * W_LD + C_TOT);
  float acc = 0.f;
#pragma unroll 4
  for (int i = 0; i < D_TOT / 4; ++i) {
    float4 a = sr[i], w = wr[i];
    acc += a.x * w.x; acc += a.y * w.y; acc += a.z * w.z; acc += a.w * w.w;
  }
  sb[(size_t)b * E_TOT + e] = acc;
}

// ---- main GEMM + fused tanh/dot epilogue ----
// BM=128 x BN=512 (full e), BK=32.  8 waves = 2(m) x 4(n); wave tile 64x128.
// Triple-buffered, ALL staging via global_load_lds (A kept fp32 in LDS,
// converted to bf16 at fragment load).  Issue distance 2: tile t issues
// A/B(t+2); one vmcnt(6) + one s_barrier per tile.  LDS 144 KB, 1 block/CU.
// Swizzle: 16B seg s of row r stored at s^(r&7) (A: 8 segs/row fp32;
// B: pair-rows of 128B, R1-verified scheme kept verbatim).
__global__ __launch_bounds__(NT, 2)
void gemm_tanh_dot_kernel(const float* __restrict__ A,
                          const bf16*  __restrict__ Wb,
                          const float* __restrict__ sb,
                          const float* __restrict__ Wv,
                          float* __restrict__ logits) {
  __shared__ __align__(16) char smem[3 * 16384 + 3 * 32768];  // 144 KB
  char* const As0 = smem;
  char* const As1 = smem + 16384;
  char* const As2 = smem + 32768;
  char* const Bs0 = smem + 49152;
  char* const Bs1 = smem + 49152 + 32768;
  char* const Bs2 = smem + 49152 + 65536;

  const int tid  = threadIdx.x;
  const int lane = tid & 63;
  const int wid  = tid >> 6;
  const int wm   = wid >> 2;         // 0..1 : m-half
  const int wn   = wid & 3;          // 0..3 : e-slice (128 e each)
  const int fr   = lane & 15;
  const int fg   = lane >> 4;
  const int m0   = blockIdx.x * BM;

  // A staging: thread -> (row=tid>>3, dest seg d=tid&7); src seg = d^(row&7).
  const int a_row = tid >> 3;        // 0..63  (second issue: +64 rows)
  const int a_sg  = (tid & 7) ^ (a_row & 7);
  const float* asrc = A + (size_t)(m0 + a_row) * C_TOT + (a_sg << 2);
  const int a_dst = tid << 4;

  // B staging (R1-verified, verbatim): linear dest, inverse-swizzled src.
  const int b_s = (tid & 7) ^ ((tid >> 3) & 7);
  const int b_e = ((tid >> 3) << 1) + (b_s >> 2);
  const bf16* bsrc = Wb + (size_t)b_e * C_TOT + ((b_s & 3) << 3);
  const int b_dst = tid << 4;

  // A fragment read: fp32 rows of 128B; row = wm*64+am*16+fr, segs 2fg,2fg+1
  // (stored ^ (fr&7)); am stride 2048.  offHi = offLo ^ 16.
  const int aoff = (wm << 13) + (fr << 7) + ((((fg << 1) ^ (fr & 7))) << 4);
  // B fragment read: bf16 pair-rows (128B); e = wn*128+bn*16+fr, k-seg fg.
  const int boff = (wn << 13) + ((fr >> 1) << 7)
                 + (((((fr & 1) << 2) | fg) ^ ((fr >> 1) & 7)) << 4);

  f32x4 acc[4][8];
#pragma unroll
  for (int i = 0; i < 4; ++i)
#pragma unroll
    for (int j = 0; j < 8; ++j)
      acc[i][j] = (f32x4){0.f, 0.f, 0.f, 0.f};

  auto stage = [&](char* Ai, char* Bi, int t) {
    const int kcA = t << 5;          // float offset = t*32
    gload_lds16(asrc + kcA, Ai + a_dst);
    gload_lds16(asrc + kcA + 65536, Ai + a_dst + 8192);  // +64 rows
    const int kcB = t << 5;          // bf16 offset = t*32
#pragma unroll
    for (int i = 0; i < 4; ++i)
      gload_lds16(bsrc + kcB + i * 131072, Bi + b_dst + i * 8192);
  };

  auto compute = [&](const char* Ac, const char* Bc) {
    bf16x8 af[4];
#pragma unroll
    for (int am = 0; am < 4; ++am) {
      const int o = aoff + am * 2048;
      f32x4 lo = *(const f32x4*)(Ac + o);
      f32x4 hi = *(const f32x4*)(Ac + (o ^ 16));
      bf16x8 f;
      f[0] = (bf16)lo[0]; f[1] = (bf16)lo[1]; f[2] = (bf16)lo[2]; f[3] = (bf16)lo[3];
      f[4] = (bf16)hi[0]; f[5] = (bf16)hi[1]; f[6] = (bf16)hi[2]; f[7] = (bf16)hi[3];
      af[am] = f;
    }
    bf16x8 bfr[8];
#pragma unroll
    for (int bn = 0; bn < 8; ++bn)
      bfr[bn] = *(const bf16x8*)(Bc + boff + bn * 1024);
#pragma unroll
    for (int am = 0; am < 4; ++am)
#pragma unroll
      for (int bn = 0; bn < 8; ++bn)
        acc[am][bn] = __builtin_amdgcn_mfma_f32_16x16x32_bf16(
            af[am], bfr[bn], acc[am][bn], 0, 0, 0);
  };

// One tile: wait [A(t),B(t)] landed (FIFO: 12 outstanding -> 6), publish via
// barrier, issue A/B(t+2), compute(t).  Never vmcnt(0) in the main loop.
#define TILE(Ac, Bc, Ai, Bi, T, DO_ISSUE, WCNT)                         \
  asm volatile("s_waitcnt vmcnt(" #WCNT ")" ::: "memory");              \
  __builtin_amdgcn_sched_barrier(0);                                    \
  __builtin_amdgcn_s_barrier();                                         \
  __builtin_amdgcn_sched_barrier(0);                                    \
  if (DO_ISSUE) stage(Ai, Bi, (T) + 2);                                 \
  compute(Ac, Bc);

  // prologue: queue = [A0 2, B0 4, A1 2, B1 4]
  stage(As0, Bs0, 0);
  stage(As1, Bs1, 1);

#pragma unroll 1
  for (int kp = 0; kp < 10; ++kp) {
    const int t0 = kp * 3;           // tiles t0..t0+2, t0+2 <= 29
    TILE(As0, Bs0, As2, Bs2, t0 + 0, true, 6);
    TILE(As1, Bs1, As0, Bs0, t0 + 1, true, 6);
    TILE(As2, Bs2, As1, Bs1, t0 + 2, true, 6);
  }
  // peeled tail: t=30 (queue 12 -> 6), t=31 (queue 6 -> 0); no new issues.
  TILE(As0, Bs0, As0, Bs0, 30, false, 6);
  TILE(As1, Bs1, As1, Bs1, 31, false, 0);
#undef TILE

  // ---- fused epilogue: +sb, tanh, *Wv, reduce over e ----
  float wv[8];
#pragma unroll
  for (int bn = 0; bn < 8; ++bn)
    wv[bn] = Wv[(wn << 7) + (bn << 4) + fr];

  // red = [4 wn][128 m] floats at smem+0 (phys A-buf0; t=31 read phys buf1 ->
  // disjoint; barrier below before the cross-wn sum).
  float* red = (float*)smem;
#pragma unroll
  for (int am = 0; am < 4; ++am) {
#pragma unroll
    for (int j = 0; j < 4; ++j) {
      const int mloc = (wm << 6) + (am << 4) + (fg << 2) + j;  // 0..127
      const int b = mloc & 63;                                  // m = l*64+b
      const float* sbr = sb + (size_t)b * E_TOT + (wn << 7) + fr;
      float c = 0.f;
#pragma unroll
      for (int bn = 0; bn < 8; ++bn)
        c += tanhf(acc[am][bn][j] + sbr[bn << 4]) * wv[bn];
      c += __shfl_xor(c, 1, 64);
      c += __shfl_xor(c, 2, 64);
      c += __shfl_xor(c, 4, 64);
      c += __shfl_xor(c, 8, 64);
      if (fr == 0) red[(wn << 7) + mloc] = c;
    }
  }
  __syncthreads();
  if (tid < BM) {
    float v = red[tid] + red[128 + tid] + red[256 + tid] + red[384 + tid];
    logits[m0 + tid] = v;
  }
}

// ---- softmax over l per b; logits[m], m = l*64+b; out[b][l] ----
__global__ __launch_bounds__(256)
void softmax_kernel(const float* __restrict__ logits, float* __restrict__ out) {
  const int b = blockIdx.x;
  const int t = threadIdx.x;
  const int lane = t & 63, w = t >> 6;
  __shared__ float sm[8];
  float x[4];
  float mx = -3.4e38f;
#pragma unroll
  for (int i = 0; i < 4; ++i) {
    const int l = t + (i << 8);
    x[i] = logits[(size_t)l * 64 + b];
    mx = fmaxf(mx, x[i]);
  }
#pragma unroll
  for (int off = 1; off < 64; off <<= 1)
    mx = fmaxf(mx, __shfl_xor(mx, off, 64));
  if (lane == 0) sm[w] = mx;
  __syncthreads();
  mx = fmaxf(fmaxf(sm[0], sm[1]), fmaxf(sm[2], sm[3]));
  float ex[4], ssum = 0.f;
#pragma unroll
  for (int i = 0; i < 4; ++i) { ex[i] = expf(x[i] - mx); ssum += ex[i]; }
#pragma unroll
  for (int off = 1; off < 64; off <<= 1)
    ssum += __shfl_xor(ssum, off, 64);
  if (lane == 0) sm[4 + w] = ssum;
  __syncthreads();
  const float inv = 1.0f / (sm[4] + sm[5] + sm[6] + sm[7]);
#pragma unroll
  for (int i = 0; i < 4; ++i)
    out[(size_t)b * 1024 + t + (i << 8)] = ex[i] * inv;
}

extern "C" void kernel_launch(void* const* d_in, const int* in_sizes, int n_in,
                              void* d_out, int out_size, void* d_ws, size_t ws_size,
                              hipStream_t stream) {
  const float* enc = (const float*)d_in[0];  // (1024, 64, 1024) fp32
  const float* s   = (const float*)d_in[1];  // (1, 64, 512)     fp32
  const float* Wat = (const float*)d_in[2];  // (512, 1536)      fp32
  const float* Wv  = (const float*)d_in[3];  // (1, 512)         fp32
  float* out = (float*)d_out;                // (64, 1024)       fp32

  char* ws = (char*)d_ws;
  bf16*  Wb     = (bf16*)ws;                                // 1 MB
  float* sb     = (float*)(ws + (1u << 20));                // 128 KB
  float* logits = (float*)(ws + (1u << 20) + (128u << 10)); // 256 KB

  convert_we_kernel<<<E_TOT, 256, 0, stream>>>(Wat, Wb);
  sb_kernel<<<E_TOT, 64, 0, stream>>>(s, Wat, sb);
  gemm_tanh_dot_kernel<<<M_TOT / BM, NT, 0, stream>>>(enc, Wb, sb, Wv, logits);
  softmax_kernel<<<B_TOT, 256, 0, stream>>>(logits, out);
}

// Round 6
// 151.059 us; speedup vs baseline: 1.2141x; 1.0652x over previous
//
#include <hip/hip_runtime.h>
#include <hip/hip_bf16.h>
#include <stdint.h>

typedef __bf16 bf16;
typedef __bf16 bf16x4 __attribute__((ext_vector_type(4)));
typedef __bf16 bf16x8 __attribute__((ext_vector_type(8)));
typedef float  f32x4  __attribute__((ext_vector_type(4)));

#define L_TOT 1024
#define B_TOT 64
#define C_TOT 1024            // ENC2 (= K)
#define D_TOT 512             // DEC
#define E_TOT 512
#define M_TOT (L_TOT * B_TOT) // 65536
#define W_LD  (C_TOT + D_TOT) // 1536

#define BM 128
#define BN 256
#define BK 64
#define NT 512
#define NKT (C_TOT / BK)      // 16

__device__ __forceinline__ void gload_lds16(const void* g, void* l) {
  __builtin_amdgcn_global_load_lds(
      (const __attribute__((address_space(1))) unsigned int*)(uintptr_t)g,
      (__attribute__((address_space(3))) unsigned int*)(uintptr_t)l,
      16, 0, 0);
}

__device__ __forceinline__ bf16x8 cvt8(f32x4 a, f32x4 b) {
  bf16x8 o;
  o[0]=(bf16)a[0]; o[1]=(bf16)a[1]; o[2]=(bf16)a[2]; o[3]=(bf16)a[3];
  o[4]=(bf16)b[0]; o[5]=(bf16)b[1]; o[6]=(bf16)b[2]; o[7]=(bf16)b[3];
  return o;
}

__device__ __forceinline__ float tanh_fast(float x) {
  // exact identity tanh(x) = 1 - 2/(e^{2x}+1); overflow-graceful at both ends.
  float e = __expf(2.0f * x);
  return 1.0f - __fdividef(2.0f, e + 1.0f);
}

// ---- prep: Wa_e (fp32, row stride 1536) -> bf16 [512][1024] in ws ----
__global__ void convert_we_kernel(const float* __restrict__ Wattn,
                                  bf16* __restrict__ Wb) {
  const int e = blockIdx.x;   // 512
  const int t = threadIdx.x;  // 256
  const float4 v = ((const float4*)(Wattn + (size_t)e * W_LD))[t];
  bf16x4 o;
  o[0]=(bf16)v.x; o[1]=(bf16)v.y; o[2]=(bf16)v.z; o[3]=(bf16)v.w;
  ((bf16x4*)(Wb + (size_t)e * C_TOT))[t] = o;
}

// ---- prep: sb[b][e] = sum_d s[b,d] * Wa_s[e,d] ----
__global__ void sb_kernel(const float* __restrict__ s,
                          const float* __restrict__ Wattn,
                          float* __restrict__ sb) {
  const int e = blockIdx.x;   // 512
  const int b = threadIdx.x;  // 64
  const float4* sr = (const float4*)(s + (size_t)b * D_TOT);
  const float4* wr = (const float4*)(Wattn + (size_t)e * W_LD + C_TOT);
  float acc = 0.f;
#pragma unroll 4
  for (int i = 0; i < D_TOT / 4; ++i) {
    float4 a = sr[i], w = wr[i];
    acc += a.x * w.x; acc += a.y * w.y; acc += a.z * w.z; acc += a.w * w.w;
  }
  sb[(size_t)b * E_TOT + e] = acc;
}

// ---- main GEMM + fused tanh/dot epilogue ----
// BM=128 x BN=256, BK=64.  8 waves = 2m x 4n, wave tile 64x64.
// A: reg-staged fp32->bf16, pair-row LDS (R1 0-conflict scheme), 2 bufs.
// B: global_load_lds, R1 scheme, 3 bufs.  LDS 128KB.
// Per tile: issue B(t+2),A(t+2); vmcnt(8) [drains t+1 exactly]; write A(t+1);
// 2 phases {8 ds_read; lgkmcnt(0); 16 MFMA}; raw barrier (no vmem drain).
__global__ __launch_bounds__(NT, 2)
void gemm_tanh_dot_kernel(const float* __restrict__ A,
                          const bf16*  __restrict__ Wb,
                          const float* __restrict__ sb,
                          const float* __restrict__ Wv,
                          float* __restrict__ logitsH) {
  __shared__ __align__(16) char smem[2 * 16384 + 3 * 32768];  // 128 KB
  char* const Aa0 = smem;
  char* const Aa1 = smem + 16384;
  char* const Bq0 = smem + 32768;
  char* const Bq1 = smem + 65536;
  char* const Bq2 = smem + 98304;

  const int tid  = threadIdx.x;
  const int lane = tid & 63;
  const int wid  = tid >> 6;
  const int wm   = wid >> 2;        // 0..1
  const int wn   = wid & 3;         // 0..3
  const int fr   = lane & 15;
  const int fg   = lane >> 4;

  const int blk = blockIdx.x;
  const int gx  = (blk & 7) | ((blk >> 4) << 3);  // pairs (b,b+8): same gx, same XCD
  const int gy  = (blk >> 3) & 1;
  const int m0  = gx << 7;
  const int e0  = gy << 8;

  // A staging: thread -> row=tid>>2 (0..127), 16 floats at k16=(tid&3)*16
  const float* gA = A + (size_t)(m0 + (tid >> 2)) * C_TOT + ((tid & 3) << 4);
  const int p_a  = tid >> 3;
  const int rb_a = (tid >> 2) & 1;
  const int hf_a = (tid >> 1) & 1;
  const int qb_a = (tid & 1) << 1;
  const int awo0 = hf_a * 8192 + p_a * 128 + ((((rb_a << 2) | qb_a))     ^ (p_a & 7)) * 16;
  const int awo1 = hf_a * 8192 + p_a * 128 + ((((rb_a << 2) | (qb_a+1))) ^ (p_a & 7)) * 16;

  // B staging (R1-verified): linear dest, inverse-swizzled src
  const int b_s = (tid & 7) ^ ((tid >> 3) & 7);
  const int b_e = ((tid >> 3) << 1) + (b_s >> 2);
  const bf16* gB = Wb + (size_t)(e0 + b_e) * C_TOT + ((b_s & 3) << 3);
  const int bdst = tid << 4;

  // fragment read offsets
  const int sx  = (((((fr & 1) << 2) | fg)) ^ (fr >> 1)) << 4;
  const int aro = ((wm << 5) + (fr >> 1)) * 128 + sx;   // + am*1024 + kk*8192
  const int bro = ((wn << 5) + (fr >> 1)) * 128 + sx;   // + bn*1024 + kk*16384

  f32x4 acc[4][4];
#pragma unroll
  for (int i = 0; i < 4; ++i)
#pragma unroll
    for (int j = 0; j < 4; ++j)
      acc[i][j] = (f32x4){0.f, 0.f, 0.f, 0.f};

  f32x4 av00, av01, av02, av03, av10, av11, av12, av13;

  auto stageB = [&](char* Bp, int t) {
    const bf16* sp = gB + (t << 6);
    gload_lds16(sp,           Bp + bdst);
    gload_lds16(sp + 131072,  Bp + bdst + 8192);
    gload_lds16(sp + 32,          Bp + bdst + 16384);
    gload_lds16(sp + 32 + 131072, Bp + bdst + 24576);
  };

#define LOADA(p, t)                                                            \
  { const float* ap_ = gA + ((t) << 6);                                        \
    asm volatile("global_load_dwordx4 %0, %1, off"           : "=v"(av##p##0) : "v"(ap_) : "memory"); \
    asm volatile("global_load_dwordx4 %0, %1, off offset:16" : "=v"(av##p##1) : "v"(ap_) : "memory"); \
    asm volatile("global_load_dwordx4 %0, %1, off offset:32" : "=v"(av##p##2) : "v"(ap_) : "memory"); \
    asm volatile("global_load_dwordx4 %0, %1, off offset:48" : "=v"(av##p##3) : "v"(ap_) : "memory"); }

#define WRITEA(Ap, p)                                                          \
  { *(bf16x8*)((Ap) + awo0) = cvt8(av##p##0, av##p##1);                        \
    *(bf16x8*)((Ap) + awo1) = cvt8(av##p##2, av##p##3); }

  auto phase = [&](int kk, const char* Ap, const char* Bp) {
    bf16x8 af[4], bf[4];
    const char* Ab = Ap + kk * 8192  + aro;
    const char* Bb = Bp + kk * 16384 + bro;
#pragma unroll
    for (int am = 0; am < 4; ++am) af[am] = *(const bf16x8*)(Ab + am * 1024);
#pragma unroll
    for (int bn = 0; bn < 4; ++bn) bf[bn] = *(const bf16x8*)(Bb + bn * 1024);
    asm volatile("s_waitcnt lgkmcnt(0)" ::: "memory");
    __builtin_amdgcn_sched_barrier(0);
    __builtin_amdgcn_s_setprio(1);
#pragma unroll
    for (int am = 0; am < 4; ++am)
#pragma unroll
      for (int bn = 0; bn < 4; ++bn)
        acc[am][bn] = __builtin_amdgcn_mfma_f32_16x16x32_bf16(
            af[am], bf[bn], acc[am][bn], 0, 0, 0);
    __builtin_amdgcn_s_setprio(0);
    __builtin_amdgcn_sched_barrier(0);
  };

#define BARRIER()                                                              \
  asm volatile("s_waitcnt lgkmcnt(0)" ::: "memory");                           \
  __builtin_amdgcn_s_barrier();                                                \
  __builtin_amdgcn_sched_barrier(0);

  // ---- prologue: Q = [B0x4, A0x4, B1x4, A1x4] -> drain 8 -> [B1, A1]
  stageB(Bq0, 0);
  LOADA(0, 0);
  stageB(Bq1, 1);
  LOADA(1, 1);
  asm volatile("s_waitcnt vmcnt(8)" ::: "memory");
  __builtin_amdgcn_sched_barrier(0);
  WRITEA(Aa0, 0);
  BARRIER();                       // tile 0 ready

  char* B0 = Bq0; char* B1 = Bq1; char* B2 = Bq2;

#pragma unroll 1
  for (int kp = 0; kp < 7; ++kp) {
    const int t = kp << 1;
    // ---- tile t (even): cur A=Aa0,B=B0; stage B(t+2)->B2, A(t+2)->av0 ----
    stageB(B2, t + 2);
    LOADA(0, t + 2);
    asm volatile("s_waitcnt vmcnt(8)" ::: "memory");   // drains B(t+1),A(t+1)
    __builtin_amdgcn_sched_barrier(0);
    WRITEA(Aa1, 1);                                    // A(t+1) -> a1
    phase(0, Aa0, B0);
    phase(1, Aa0, B0);
    BARRIER();
    // ---- tile t+1 (odd): cur A=Aa1,B=B1; stage B(t+3)->B0, A(t+3)->av1 ----
    stageB(B0, t + 3);
    LOADA(1, t + 3);
    asm volatile("s_waitcnt vmcnt(8)" ::: "memory");   // drains B(t+2),A(t+2)
    __builtin_amdgcn_sched_barrier(0);
    WRITEA(Aa0, 0);                                    // A(t+2) -> a0
    phase(0, Aa1, B1);
    phase(1, Aa1, B1);
    BARRIER();
    // rotate: (B0,B1,B2) <- (B2,B0,B1)
    char* tmp = B2; B2 = B1; B1 = B0; B0 = tmp;
  }

  // ---- tile 14: cur A=Aa0, B=B0(=b[2]); write A(15); no new issues ----
  asm volatile("s_waitcnt vmcnt(0)" ::: "memory");     // tail drain (A15,B15)
  __builtin_amdgcn_sched_barrier(0);
  WRITEA(Aa1, 1);
  phase(0, Aa0, B0);
  phase(1, Aa0, B0);
  BARRIER();
  // ---- tile 15: cur A=Aa1, B=B1(=b[0]) ----
  phase(0, Aa1, B1);
  phase(1, Aa1, B1);

  // ---- fused epilogue: +sb, tanh, *Wv, reduce over this block's 256 e ----
  float wv[4];
#pragma unroll
  for (int bn = 0; bn < 4; ++bn)
    wv[bn] = Wv[e0 + (wn << 6) + (bn << 4) + fr];

  float* red = (float*)smem;  // [4 wn][128 m] in Aa0 region (tile15 used Aa1/B1)
#pragma unroll
  for (int am = 0; am < 4; ++am) {
#pragma unroll
    for (int j = 0; j < 4; ++j) {
      const int mloc = (wm << 6) + (am << 4) + (fg << 2) + j;  // 0..127
      const int bi = mloc & 63;                                // m = l*64+b
      const float* sbr = sb + (size_t)bi * E_TOT + e0 + (wn << 6) + fr;
      float c = 0.f;
#pragma unroll
      for (int bn = 0; bn < 4; ++bn)
        c += tanh_fast(acc[am][bn][j] + sbr[bn << 4]) * wv[bn];
      c += __shfl_xor(c, 1, 64);
      c += __shfl_xor(c, 2, 64);
      c += __shfl_xor(c, 4, 64);
      c += __shfl_xor(c, 8, 64);
      if (fr == 0) red[(wn << 7) + mloc] = c;
    }
  }
  __syncthreads();
  if (tid < BM) {
    float v = red[tid] + red[128 + tid] + red[256 + tid] + red[384 + tid];
    logitsH[(size_t)gy * M_TOT + m0 + tid] = v;
  }
#undef LOADA
#undef WRITEA
#undef BARRIER
}

// ---- softmax over l per b; logits[m] = lH0[m]+lH1[m], m = l*64+b ----
__global__ __launch_bounds__(256)
void softmax_kernel(const float* __restrict__ lH, float* __restrict__ out) {
  const int b = blockIdx.x;
  const int t = threadIdx.x;
  const int lane = t & 63, w = t >> 6;
  __shared__ float sm[8];
  float x[4];
  float mx = -3.4e38f;
#pragma unroll
  for (int i = 0; i < 4; ++i) {
    const int m = (t + (i << 8)) * 64 + b;
    x[i] = lH[m] + lH[M_TOT + m];
    mx = fmaxf(mx, x[i]);
  }
#pragma unroll
  for (int off = 1; off < 64; off <<= 1)
    mx = fmaxf(mx, __shfl_xor(mx, off, 64));
  if (lane == 0) sm[w] = mx;
  __syncthreads();
  mx = fmaxf(fmaxf(sm[0], sm[1]), fmaxf(sm[2], sm[3]));
  float ex[4], ssum = 0.f;
#pragma unroll
  for (int i = 0; i < 4; ++i) { ex[i] = __expf(x[i] - mx); ssum += ex[i]; }
#pragma unroll
  for (int off = 1; off < 64; off <<= 1)
    ssum += __shfl_xor(ssum, off, 64);
  if (lane == 0) sm[4 + w] = ssum;
  __syncthreads();
  const float inv = 1.0f / (sm[4] + sm[5] + sm[6] + sm[7]);
#pragma unroll
  for (int i = 0; i < 4; ++i)
    out[(size_t)b * 1024 + t + (i << 8)] = ex[i] * inv;
}

extern "C" void kernel_launch(void* const* d_in, const int* in_sizes, int n_in,
                              void* d_out, int out_size, void* d_ws, size_t ws_size,
                              hipStream_t stream) {
  const float* enc = (const float*)d_in[0];  // (1024, 64, 1024) fp32
  const float* s   = (const float*)d_in[1];  // (1, 64, 512)     fp32
  const float* Wat = (const float*)d_in[2];  // (512, 1536)      fp32
  const float* Wv  = (const float*)d_in[3];  // (1, 512)         fp32
  float* out = (float*)d_out;                // (64, 1024)       fp32

  char* ws = (char*)d_ws;
  bf16*  Wb      = (bf16*)ws;                                 // 1 MB
  float* sb      = (float*)(ws + (1u << 20));                 // 128 KB
  float* logitsH = (float*)(ws + (1u << 20) + (128u << 10));  // 512 KB (2 halves)

  convert_we_kernel<<<E_TOT, 256, 0, stream>>>(Wat, Wb);
  sb_kernel<<<E_TOT, 64, 0, stream>>>(s, Wat, sb);
  gemm_tanh_dot_kernel<<<(M_TOT / BM) * 2, NT, 0, stream>>>(enc, Wb, sb, Wv, logitsH);
  softmax_kernel<<<B_TOT, 256, 0, stream>>>(logitsH, out);
}